// Round 7
// baseline (167.142 us; speedup 1.0000x reference)
//
#include <hip/hip_runtime.h>

constexpr int kB  = 16;
constexpr int kM  = 512;
constexpr int kS  = 32;
constexpr int kE  = 128;
constexpr int kV  = 32000;
constexpr int kVN = kV - 1;   // nil (zero) row index
constexpr int kMS = 132;      // padded LDS stride for hops mem tile

// -------------------------------------------------------------------------
// Kernel 1: story embeddings via LDS-DMA gather (global_load_lds, width 16).
// Hypothesis under test: the ~41 µs embed wall is the per-CU outstanding-
// miss cap on the VGPR-return load path (16K lines/CU x 400cyc / 64 MSHR
// = 42 µs); the fire-and-forget DMA path may allow more lines in flight.
// Block = 2 rows, 256 threads (4 waves). Per s-chunk (8 s): 16 DMA
// instructions (wave w issues 4), each staging one (s,table) pair's two
// 512 B rows into a 1 KB LDS slot (lanes 0-31 row0, 32-63 row1). Then
// threads (tab = t>>7, e = t&127) accumulate both rows from LDS.
// enc[s][e] = 1 + (e-63)(s-15)/1024 (exact f32 match of numpy formula).
// Block 0 zeroes the hops barrier counters.
// -------------------------------------------------------------------------
__global__ __launch_bounds__(256) void embed_stories_kernel(
    const int*   __restrict__ stories,   // [B,M,S]
    const float* __restrict__ st_bias,   // [VN,E]
    const float* __restrict__ out_bias,  // [VN,E]
    const float* __restrict__ mem_bias,  // [M,E]
    float*       __restrict__ memory,    // [B,M,E]
    float*       __restrict__ output,    // [B,M,E]
    unsigned*    __restrict__ bar)       // [B] counters -> zeroed by block 0
{
    __shared__ int sidx[2][kS];
    __shared__ __align__(16) float stage[16 * 256];  // [8 s][2 tab][2 row][128]

    const int t = threadIdx.x;
    if (t < 64) sidx[t >> 5][t & 31] = stories[blockIdx.x * 2 * kS + t];
    if (blockIdx.x == 0 && t < kB) bar[t] = 0u;
    __syncthreads();

    const int wave = t >> 6;
    const int lane = t & 63;
    const int half = lane >> 5;      // row of the pair this lane stages
    const int l16  = lane & 31;      // 16-byte unit within the row

    const int tab = t >> 7;          // compute-phase: table (0=mem,1=out)
    const int e   = t & 127;
    const float ef = (float)(e - 63) * (1.0f / 1024.0f);
    float acc0 = 0.f, acc1 = 0.f;    // rows 0,1 of the pair, own table

    for (int c = 0; c < 4; ++c) {
        // ---- stage chunk c: 16 DMA instructions, 4 per wave ----
        #pragma unroll
        for (int k = 0; k < 4; ++k) {
            const int idx4 = wave * 4 + k;        // 0..15
            const int sl   = idx4 >> 1;           // s_local 0..7
            const int tb   = idx4 & 1;
            const int s    = c * 8 + sl;
            const int widx = sidx[half][s];
            const int ci   = widx < kVN ? widx : (kVN - 1);
            const float* g = (tb ? out_bias : st_bias)
                             + (size_t)ci * kE + l16 * 4;
            float* lb = &stage[(sl * 2 + tb) * 256];   // wave-uniform base
            __builtin_amdgcn_global_load_lds(
                (const __attribute__((address_space(1))) void*)g,
                (__attribute__((address_space(3))) void*)lb, 16, 0, 0);
        }
        __syncthreads();   // drain DMA, publish stage

        // ---- accumulate chunk c from LDS ----
        #pragma unroll
        for (int sl = 0; sl < 8; ++sl) {
            const int s = c * 8 + sl;
            const float enc = fmaf(ef, (float)(s - 15), 1.0f);
            const float l0 = (sidx[0][s] < kVN) ? enc : 0.f;
            const float l1 = (sidx[1][s] < kVN) ? enc : 0.f;
            const float* sp = &stage[(sl * 2 + tab) * 256];
            acc0 = fmaf(sp[e],       l0, acc0);
            acc1 = fmaf(sp[128 + e], l1, acc1);
        }
        __syncthreads();   // protect stage before next chunk overwrites
    }

    const int row0 = blockIdx.x * 2;
    if (tab == 0) {
        const int m0 = row0 & (kM - 1);
        memory[(size_t)row0 * kE + e]       = acc0 + mem_bias[m0 * kE + e];
        memory[(size_t)(row0 + 1) * kE + e] = acc1 + mem_bias[(m0 + 1) * kE + e];
    } else {
        output[(size_t)row0 * kE + e]       = acc0;
        output[(size_t)(row0 + 1) * kE + e] = acc1;
    }
}

// -------------------------------------------------------------------------
// Fence-free 4-block spin barrier (R4/R6-proven). Co-residency: 64 blocks
// on 256 CUs under a REGULAR launch. Cross-block data via agent-scope
// RELAXED atomics (no cache-maintenance storms — R3 lesson).
// -------------------------------------------------------------------------
__device__ __forceinline__ void group_barrier(unsigned* ctr, unsigned target)
{
    __syncthreads();
    if (threadIdx.x == 0) {
        __hip_atomic_fetch_add(ctr, 1u, __ATOMIC_RELEASE, __HIP_MEMORY_SCOPE_AGENT);
        while (__hip_atomic_load(ctr, __ATOMIC_RELAXED, __HIP_MEMORY_SCOPE_AGENT) < target)
            __builtin_amdgcn_s_sleep(2);
    }
    __syncthreads();
}
__device__ __forceinline__ void cstore(float* p, float v) {
    __hip_atomic_store(p, v, __ATOMIC_RELAXED, __HIP_MEMORY_SCOPE_AGENT);
}
__device__ __forceinline__ float cload(const float* p) {
    return __hip_atomic_load(p, __ATOMIC_RELAXED, __HIP_MEMORY_SCOPE_AGENT);
}

// -------------------------------------------------------------------------
// Kernel 2 (REGULAR launch, 64 blocks x 1024 threads): q-embed + 3 hops.
// (unchanged from R6 — passed, ~<40 µs)
// -------------------------------------------------------------------------
__global__ __launch_bounds__(1024) void hops_kernel(
    const int*   __restrict__ queries,   // [B,S]
    const float* __restrict__ q_bias,    // [VN,E]
    const float* __restrict__ memory,    // [B,M,E]
    const float* __restrict__ output,    // [B,M,E]
    const float* __restrict__ w_int,     // [E,E]
    const float* __restrict__ w_out,     // [E,E]
    float*       __restrict__ numer,     // [2,B,4,E]
    float*       __restrict__ denom,     // [2,B,4]
    float*       __restrict__ xg,        // [E,B] transposed
    unsigned*    __restrict__ bar)       // [B] counters (zeroed by embed)
{
    __shared__ __align__(16) float mem_lds[128 * kMS];
    __shared__ __align__(16) float out_lds[128 * kE];
    __shared__ float sc_q[128];
    __shared__ __align__(16) float q_s[kE];
    __shared__ float xb[kE];
    __shared__ __align__(16) float part8[8][kE];
    __shared__ int qidx[kS];

    const int bid = blockIdx.x;
    const int b   = bid >> 2;
    const int qtr = bid & 3;
    const int t   = threadIdx.x;
    unsigned* ctr = bar + b;

    const float* memb = memory + ((size_t)b * kM + qtr * 128) * kE;
    const float* outb = output + ((size_t)b * kM + qtr * 128) * kE;
    #pragma unroll
    for (int i = 0; i < 4; ++i) {
        const int flat = t + i * 1024;
        const int rr = flat >> 5, ff = (flat & 31) * 4;
        *(float4*)&mem_lds[rr * kMS + ff] = *(const float4*)&memb[(size_t)rr * kE + ff];
        *(float4*)&out_lds[rr * kE  + ff] = *(const float4*)&outb[(size_t)rr * kE + ff];
    }
    if (t < kS) qidx[t] = queries[b * kS + t];
    __syncthreads();

    if (t < 256) {
        const int g = t >> 5, lane = t & 31, e0 = lane * 4;
        const float f0 = (float)(e0 - 63) * (1.0f / 1024.0f);
        const float f1 = (float)(e0 - 62) * (1.0f / 1024.0f);
        const float f2 = (float)(e0 - 61) * (1.0f / 1024.0f);
        const float f3 = (float)(e0 - 60) * (1.0f / 1024.0f);
        float4 a = {0.f, 0.f, 0.f, 0.f};
        #pragma unroll
        for (int j = 0; j < 4; ++j) {
            const int s   = g * 4 + j;
            const int idx = qidx[s];
            const int ci  = idx < kVN ? idx : (kVN - 1);
            const float live = (idx < kVN) ? 1.0f : 0.0f;
            const float sf = (float)(s - 15);
            const float4 v = *(const float4*)&q_bias[(size_t)ci * kE + e0];
            a.x = fmaf(v.x, fmaf(f0, sf, 1.f) * live, a.x);
            a.y = fmaf(v.y, fmaf(f1, sf, 1.f) * live, a.y);
            a.z = fmaf(v.z, fmaf(f2, sf, 1.f) * live, a.z);
            a.w = fmaf(v.w, fmaf(f3, sf, 1.f) * live, a.w);
        }
        *(float4*)&part8[g][e0] = a;
    }
    __syncthreads();
    if (t < kE) {
        float s = 0.f;
        #pragma unroll
        for (int g = 0; g < 8; ++g) s += part8[g][t];
        q_s[t] = s;
    }
    __syncthreads();

    const int grp = t >> 7;
    const int e   = t & 127;

    for (int hop = 0; hop < 3; ++hop) {
        {
            const int rw = t >> 3, sub = t & 7;
            const float4* qv = (const float4*)&q_s[sub * 16];
            const float4* mv = (const float4*)&mem_lds[rw * kMS + sub * 16];
            float d = 0.f;
            #pragma unroll
            for (int i = 0; i < 4; ++i) {
                const float4 m4 = mv[i], q4 = qv[i];
                d = fmaf(m4.x, q4.x, d); d = fmaf(m4.y, q4.y, d);
                d = fmaf(m4.z, q4.z, d); d = fmaf(m4.w, q4.w, d);
            }
            d += __shfl_down(d, 4);
            d += __shfl_down(d, 2);
            d += __shfl_down(d, 1);
            if (sub == 0) sc_q[rw] = __expf(d);   // no max-sub: |s| = O(1)
        }
        __syncthreads();

        {
            float acc = 0.f;
            const float* pp = &sc_q[grp * 16];
            const float* ob = &out_lds[grp * 16 * kE + e];
            #pragma unroll
            for (int j = 0; j < 16; ++j)
                acc = fmaf(pp[j], ob[j * kE], acc);
            part8[grp][e] = acc;
        }
        __syncthreads();

        const int pb = hop & 1;
        float* nq = numer + (((size_t)pb * kB + b) * 4 + qtr) * kE;
        if (t < kE) {
            float s = 0.f;
            #pragma unroll
            for (int g = 0; g < 8; ++g) s += part8[g][t];
            cstore(&nq[t], s);
        } else if (t < 192) {
            const int l = t - 128;
            float s2 = sc_q[l] + sc_q[l + 64];
            #pragma unroll
            for (int off = 32; off; off >>= 1) s2 += __shfl_down(s2, off);
            if (l == 0) cstore(&denom[((size_t)pb * kB + b) * 4 + qtr], s2);
        }

        group_barrier(ctr, 4u * (hop + 1));

        if (t < kE) {
            const float* nn = numer + ((size_t)pb * kB + b) * 4 * kE;
            const float* dd = denom + ((size_t)pb * kB + b) * 4;
            const float ns = cload(&nn[t]) + cload(&nn[kE + t]) +
                             cload(&nn[2 * kE + t]) + cload(&nn[3 * kE + t]);
            const float ds = cload(&dd[0]) + cload(&dd[1]) +
                             cload(&dd[2]) + cload(&dd[3]);
            xb[t] = q_s[t] + ns / ds;
        }
        __syncthreads();

        {
            const float* w = (hop == 2) ? w_out : w_int;
            float acc = 0.f;
            #pragma unroll
            for (int j = 0; j < 16; ++j) {
                const int k = grp * 16 + j;
                acc = fmaf(xb[k], w[k * kE + e], acc);
            }
            part8[grp][e] = acc;
        }
        __syncthreads();
        if (t < kE) {
            float s = 0.f;
            #pragma unroll
            for (int g = 0; g < 8; ++g) s += part8[g][t];
            q_s[t] = s;
        }
        __syncthreads();
    }

    if (qtr == 0 && t < kE) xg[t * kB + b] = fmaxf(q_s[t], 0.f);
}

// -------------------------------------------------------------------------
// Kernel 3: out[b,v] = sum_e relu_x[b,e] * w_final[e,v]. (unchanged R6)
// -------------------------------------------------------------------------
__global__ __launch_bounds__(256) void final_kernel(
    const float* __restrict__ xg,   // [E,B]
    const float* __restrict__ wf,   // [E,V]
    float*       __restrict__ out)  // [B,V]
{
    __shared__ float ps[128 * kB];
    const int t = threadIdx.x;
    const int v = blockIdx.x * 128 + (t & 127);
    const int h = t >> 7;

    float acc[kB];
    #pragma unroll
    for (int b = 0; b < kB; ++b) acc[b] = 0.f;

    const int e0 = h * 64;
    #pragma unroll 4
    for (int ei = 0; ei < 64; ++ei) {
        const int e = e0 + ei;
        const float wv = wf[(size_t)e * kV + v];
        const float* xr = xg + e * kB;
        #pragma unroll
        for (int b = 0; b < kB; ++b) acc[b] = fmaf(xr[b], wv, acc[b]);
    }
    if (h == 1) {
        #pragma unroll
        for (int b = 0; b < kB; ++b) ps[(t & 127) * kB + b] = acc[b];
    }
    __syncthreads();
    if (h == 0) {
        #pragma unroll
        for (int b = 0; b < kB; ++b)
            out[(size_t)b * kV + v] = acc[b] + ps[(t & 127) * kB + b];
    }
}

// -------------------------------------------------------------------------
extern "C" void kernel_launch(void* const* d_in, const int* in_sizes, int n_in,
                              void* d_out, int out_size, void* d_ws, size_t ws_size,
                              hipStream_t stream)
{
    const int*   queries  = (const int*)  d_in[0];
    const int*   stories  = (const int*)  d_in[1];
    const float* q_bias   = (const float*)d_in[2];
    const float* st_bias  = (const float*)d_in[3];
    const float* mem_bias = (const float*)d_in[4];
    const float* out_bias = (const float*)d_in[5];
    const float* w_int    = (const float*)d_in[6];
    const float* w_out    = (const float*)d_in[7];
    const float* w_final  = (const float*)d_in[8];
    float* out = (float*)d_out;

    // ws layout (floats): memory | output | numer | denom | xg | bar
    float* memory = (float*)d_ws;
    float* output = memory + (size_t)kB * kM * kE;        // 1,048,576
    float* numer  = output + (size_t)kB * kM * kE;        // 1,048,576
    float* denom  = numer  + 2 * kB * 4 * kE;             // 16,384
    float* xg     = denom  + 2 * kB * 4;                  // 128
    unsigned* bar = (unsigned*)(xg + kE * kB);            // 2,048

    embed_stories_kernel<<<dim3((kB * kM) / 2), dim3(256), 0, stream>>>(
        stories, st_bias, out_bias, mem_bias, memory, output, bar);

    hops_kernel<<<dim3(64), dim3(1024), 0, stream>>>(
        queries, q_bias, memory, output, w_int, w_out,
        numer, denom, xg, bar);

    final_kernel<<<dim3(kV / 128), dim3(256), 0, stream>>>(xg, w_final, out);
}